// Round 7
// baseline (694.521 us; speedup 1.0000x reference)
//
#include <hip/hip_runtime.h>

// Problem constants (match reference)
constexpr int NGPH = 128;            // graphs per batch
constexpr int NPG  = 1024;           // nodes per graph
constexpr int NN   = NGPH * NPG;     // 131072 nodes
constexpr int HD   = 128;            // feature width (FIN == H == 128)
constexpr int EPG  = 16384;          // edges per graph (E // B), contiguous per graph
constexpr int KS1 = 820, KS2 = 656, KS3 = 525;

typedef _Float16 half8v __attribute__((ext_vector_type(8)));
typedef float f32x4 __attribute__((ext_vector_type(4)));

// ---------------------------------------------------------------------------
// gate = 1.0 for all nodes (ws is poisoned 0xAA before each call).
__global__ __launch_bounds__(256) void init_gate(float* __restrict__ gate) {
  int i = blockIdx.x * 256 + threadIdx.x;
  if (i < NN) gate[i] = 1.0f;
}

// ---------------------------------------------------------------------------
// Convert all 3 layers' [Wl|Wr] (fp32) to fp16 hi/lo planes:
// Wc[layer][plane][n][k], plane 0 = hi, 1 = lo; k<128 -> Wl, k>=128 -> Wr.
__global__ __launch_bounds__(256) void wconv(const float* __restrict__ Wl0, const float* __restrict__ Wr0,
                                             const float* __restrict__ Wl1, const float* __restrict__ Wr1,
                                             const float* __restrict__ Wl2, const float* __restrict__ Wr2,
                                             _Float16* __restrict__ Wc) {
  int tid = blockIdx.x * 256 + threadIdx.x;      // 3*32768
  int layer = tid >> 15;
  int idx = tid & 32767;
  int n = idx >> 8, k = idx & 255;
  const float* Wlp = layer == 0 ? Wl0 : layer == 1 ? Wl1 : Wl2;
  const float* Wrp = layer == 0 ? Wr0 : layer == 1 ? Wr1 : Wr2;
  float v = (k < 128) ? Wlp[n * 128 + k] : Wrp[n * 128 + k - 128];
  _Float16 h = (_Float16)v;
  _Float16 l = (_Float16)(v - (float)h);
  size_t base = (size_t)layer * 65536;
  Wc[base + (size_t)n * 256 + k] = h;
  Wc[base + 32768 + (size_t)n * 256 + k] = l;
}

// ---------------------------------------------------------------------------
// Build per-graph incoming-CSR (counting sort by dst). One block per graph.
// Stages only src (ushort local ids) in LDS; dst re-read from L2 in pass 2.
// Output overwrites the graph's own src-half of edge_index (dead afterwards;
// harness restores d_in before every launch):
//   [g*64KB, +32KB) : src_sorted ushort[16384];  [+32KB, +2KB) : rs ushort[1024]
__global__ __launch_bounds__(1024) void csr_build(int* __restrict__ ei) {
  __shared__ unsigned short sloc[EPG];   // 32 KB
  __shared__ int cnt[NPG];
  __shared__ int scn[NPG];
  __shared__ int off[NPG];
  int g = blockIdx.x, t = threadIdx.x;
  const int* srcg = ei + (size_t)g * EPG;
  const int* dstg = ei + (size_t)NGPH * EPG + (size_t)g * EPG;
  cnt[t] = 0;
  for (int i = t; i < EPG; i += 1024)
    sloc[i] = (unsigned short)(srcg[i] - (g << 10));
  __syncthreads();
  for (int i = t; i < EPG; i += 1024)
    atomicAdd(&cnt[dstg[i] - (g << 10)], 1);
  __syncthreads();
  // inclusive Hillis-Steele scan over 1024, one element per thread
  int* a = cnt; int* b = scn;
  for (int d = 1; d < NPG; d <<= 1) {
    b[t] = a[t] + (t >= d ? a[t - d] : 0);
    __syncthreads();
    int* tmp = a; a = b; b = tmp;
  }
  unsigned short* ssort = (unsigned short*)(ei + (size_t)g * EPG);
  unsigned short* rsout = ssort + EPG;
  int ex = t ? a[t - 1] : 0;
  rsout[t] = (unsigned short)ex;
  off[t] = ex;
  __syncthreads();
  for (int i = t; i < EPG; i += 1024) {
    int d = dstg[i] - (g << 10);
    int pos = atomicAdd(&off[d], 1);
    ssort[pos] = sloc[i];
  }
}

// ---------------------------------------------------------------------------
// Mean aggregation, ONE WAVE PER ROW. Row index is wave-uniform, so CSR
// range, edge ids, and gate values all live in SGPRs (readfirstlane) —
// no shfl, no per-lane address math, no divergence. Lane covers 2 feats
// (float2), 64 lanes = 128 feats = 512 B per gather instruction.
// XCD swizzle: xcd = blockIdx&7 -> graphs {xcd, xcd+8, ...} so each XCD
// streams one 512 KB graph slice at a time (L2-resident).
__global__ __launch_bounds__(256) void agg3_kernel(const float* __restrict__ X,
                                                   const int* __restrict__ ei,
                                                   const float* __restrict__ gate,
                                                   float* __restrict__ Mout) {
  int t = threadIdx.x;
  int w = t >> 6, lane = t & 63;
  int xcd = blockIdx.x & 7, u = blockIdx.x >> 3;
  int g = __builtin_amdgcn_readfirstlane(xcd + 8 * (u >> 8));
  int r = __builtin_amdgcn_readfirstlane((u & 255) * 4 + w);
  const unsigned short* ss  = (const unsigned short*)(ei + (size_t)g * EPG);
  const unsigned short* rsg = ss + EPG;
  int start = __builtin_amdgcn_readfirstlane((int)rsg[r]);
  int end   = (r < 1023) ? (int)rsg[r + 1] : EPG;
  end = __builtin_amdgcn_readfirstlane(end);
  int gb = g << 10;
  const float2* X2 = (const float2*)X;
  float2 acc = make_float2(0.f, 0.f);
  float deg = 0.f;
  int e = start;
  for (; e + 4 <= end; e += 4) {
    int i0 = __builtin_amdgcn_readfirstlane((int)ss[e]);
    int i1 = __builtin_amdgcn_readfirstlane((int)ss[e + 1]);
    int i2 = __builtin_amdgcn_readfirstlane((int)ss[e + 2]);
    int i3 = __builtin_amdgcn_readfirstlane((int)ss[e + 3]);
    float g0 = gate[gb + i0], g1 = gate[gb + i1];
    float g2 = gate[gb + i2], g3 = gate[gb + i3];
    float2 v0 = X2[(size_t)(gb + i0) * 64 + lane];
    float2 v1 = X2[(size_t)(gb + i1) * 64 + lane];
    float2 v2 = X2[(size_t)(gb + i2) * 64 + lane];
    float2 v3 = X2[(size_t)(gb + i3) * 64 + lane];
    acc.x += v0.x * g0 + v1.x * g1 + v2.x * g2 + v3.x * g3;
    acc.y += v0.y * g0 + v1.y * g1 + v2.y * g2 + v3.y * g3;
    deg += ((g0 != 0.f) ? 1.f : 0.f) + ((g1 != 0.f) ? 1.f : 0.f)
         + ((g2 != 0.f) ? 1.f : 0.f) + ((g3 != 0.f) ? 1.f : 0.f);
  }
  for (; e < end; ++e) {
    int i0 = __builtin_amdgcn_readfirstlane((int)ss[e]);
    float g0 = gate[gb + i0];
    float2 v0 = X2[(size_t)(gb + i0) * 64 + lane];
    acc.x += v0.x * g0; acc.y += v0.y * g0;
    deg += (g0 != 0.f) ? 1.f : 0.f;
  }
  float inv = 1.0f / fmaxf(deg, 1.0f);
  acc.x *= inv; acc.y *= inv;
  ((float2*)Mout)[(size_t)(gb + r) * 64 + lane] = acc;
}

// ---------------------------------------------------------------------------
// Hout = relu( S @ Wl^T + (X*gate) @ Wr^T + bias ) via fp16-split MFMA, plus
// fused score[node] = relu(H).wp. W pre-converted to fp16 hi/lo planes (Wc).
// 128x128 tile/block, 4 waves 2x2, each 64x64 as 4x4 of 16x16x32 f16 MFMAs,
// products hh+hl+lh. LDA=34 (odd 17-bank stride) + b128 staging writes.
constexpr int LDA = 34;   // fp16 elements per LDS row (32 + 2 pad)
__global__ __launch_bounds__(256, 4) void gemm_mfma(const float* S,
                                                    const float* __restrict__ X,
                                                    const _Float16* __restrict__ Wc,
                                                    const float* __restrict__ bb,
                                                    const float* __restrict__ wp,
                                                    const float* __restrict__ gate,
                                                    float* Hout,
                                                    float* __restrict__ score) {
  __shared__ _Float16 Ah[128 * LDA];
  __shared__ _Float16 Al[128 * LDA];
  __shared__ _Float16 Bh[128 * LDA];
  __shared__ _Float16 Bl[128 * LDA];
  __shared__ float sc_s[128];
  int t = threadIdx.x;
  int r0 = blockIdx.x * 128;
  int lane = t & 63, wid = t >> 6;
  int wm = wid & 1, wn = wid >> 1;
  int quad = lane >> 4, mr = lane & 15;
  const _Float16* WH = Wc;
  const _Float16* WL = Wc + 32768;

  f32x4 acc[4][4];
#pragma unroll
  for (int i = 0; i < 4; ++i)
#pragma unroll
    for (int j = 0; j < 4; ++j) acc[i][j] = (f32x4){0.f, 0.f, 0.f, 0.f};

  for (int ks = 0; ks < 256; ks += 32) {
    bool isS = (ks < 128);
    // ---- stage A (fp32 -> hi/lo fp16), 128 rows x 32 k, b128 writes
    const float* Asrc = isS ? (S + (size_t)r0 * HD + ks)
                            : (X + (size_t)r0 * HD + (ks - 128));
#pragma unroll
    for (int i = 0; i < 2; ++i) {
      int slot = t + i * 256;          // 0..511, 8 floats each
      int row = slot >> 2;
      int kq = (slot & 3) * 8;
      float4 v0 = *(const float4*)&Asrc[(size_t)row * HD + kq];
      float4 v1 = *(const float4*)&Asrc[(size_t)row * HD + kq + 4];
      if (!isS) {
        float gv = gate[r0 + row];
        v0.x *= gv; v0.y *= gv; v0.z *= gv; v0.w *= gv;
        v1.x *= gv; v1.y *= gv; v1.z *= gv; v1.w *= gv;
      }
      half8v h, l;
      h[0] = (_Float16)v0.x; h[1] = (_Float16)v0.y; h[2] = (_Float16)v0.z; h[3] = (_Float16)v0.w;
      h[4] = (_Float16)v1.x; h[5] = (_Float16)v1.y; h[6] = (_Float16)v1.z; h[7] = (_Float16)v1.w;
      l[0] = (_Float16)(v0.x - (float)h[0]); l[1] = (_Float16)(v0.y - (float)h[1]);
      l[2] = (_Float16)(v0.z - (float)h[2]); l[3] = (_Float16)(v0.w - (float)h[3]);
      l[4] = (_Float16)(v1.x - (float)h[4]); l[5] = (_Float16)(v1.y - (float)h[5]);
      l[6] = (_Float16)(v1.z - (float)h[6]); l[7] = (_Float16)(v1.w - (float)h[7]);
      *(half8v*)&Ah[row * LDA + kq] = h;
      *(half8v*)&Al[row * LDA + kq] = l;
    }
    // ---- stage B (pre-converted fp16 planes), b128 copies
#pragma unroll
    for (int i = 0; i < 2; ++i) {
      int slot = t + i * 256;
      int n = slot >> 2;
      int kq = (slot & 3) * 8;
      *(half8v*)&Bh[n * LDA + kq] = *(const half8v*)&WH[(size_t)n * 256 + ks + kq];
      *(half8v*)&Bl[n * LDA + kq] = *(const half8v*)&WL[(size_t)n * 256 + ks + kq];
    }
    __syncthreads();
    // ---- fragments + MFMA
    half8v af[4], alf[4], bf[4], blf[4];
#pragma unroll
    for (int i = 0; i < 4; ++i) {
      int rowA = (wm * 64 + i * 16 + mr) * LDA + quad * 8;
      af[i]  = *(const half8v*)&Ah[rowA];
      alf[i] = *(const half8v*)&Al[rowA];
    }
#pragma unroll
    for (int j = 0; j < 4; ++j) {
      int rowW = (wn * 64 + j * 16 + mr) * LDA + quad * 8;
      bf[j]  = *(const half8v*)&Bh[rowW];
      blf[j] = *(const half8v*)&Bl[rowW];
    }
#pragma unroll
    for (int i = 0; i < 4; ++i)
#pragma unroll
      for (int j = 0; j < 4; ++j) {
        acc[i][j] = __builtin_amdgcn_mfma_f32_16x16x32_f16(af[i],  bf[j],  acc[i][j], 0, 0, 0);
        acc[i][j] = __builtin_amdgcn_mfma_f32_16x16x32_f16(af[i],  blf[j], acc[i][j], 0, 0, 0);
        acc[i][j] = __builtin_amdgcn_mfma_f32_16x16x32_f16(alf[i], bf[j],  acc[i][j], 0, 0, 0);
      }
    __syncthreads();
  }
  // ---- epilogue: bias + relu + H store + fused score = relu(H).wp
  if (t < 128) sc_s[t] = 0.f;
  __syncthreads();
  float p[4][4];
#pragma unroll
  for (int i = 0; i < 4; ++i)
#pragma unroll
    for (int r = 0; r < 4; ++r) p[i][r] = 0.f;
#pragma unroll
  for (int j = 0; j < 4; ++j) {
    int col = wn * 64 + j * 16 + mr;
    float bias = bb[col];
    float wv = wp[col];
#pragma unroll
    for (int i = 0; i < 4; ++i) {
      int rowg = r0 + wm * 64 + i * 16 + quad * 4;
#pragma unroll
      for (int r = 0; r < 4; ++r) {
        float ho = fmaxf(acc[i][j][r] + bias, 0.f);
        Hout[(size_t)(rowg + r) * HD + col] = ho;
        p[i][r] += ho * wv;
      }
    }
  }
#pragma unroll
  for (int i = 0; i < 4; ++i)
#pragma unroll
    for (int r = 0; r < 4; ++r) {
#pragma unroll
      for (int m = 1; m <= 8; m <<= 1) p[i][r] += __shfl_xor(p[i][r], m, 16);
      if (mr == 0) atomicAdd(&sc_s[wm * 64 + i * 16 + quad * 4 + r], p[i][r]);
    }
  __syncthreads();
  if (t < 128) score[r0 + t] = sc_s[t];
}

// ---------------------------------------------------------------------------
// Per-graph: normalize scores, bitonic-sort alive-masked scores, threshold at
// kth largest, write gate = tanh(s) for kept nodes else 0.
__global__ __launch_bounds__(256) void topk_kernel(const float* __restrict__ score,
                                                   float* __restrict__ gate,
                                                   const float* __restrict__ wp,
                                                   int kk) {
  __shared__ float sc[NPG];
  __shared__ float srt[NPG];
  __shared__ float shv[1];
  int g = blockIdx.x, t = threadIdx.x;
  if (t == 0) {
    float ss = 0.f;
    for (int i = 0; i < HD; ++i) ss += wp[i] * wp[i];
    shv[0] = 1.0f / (sqrtf(ss) + 1e-16f);
  }
  __syncthreads();
  float inv = shv[0];
#pragma unroll
  for (int q = 0; q < 4; ++q) {
    int n = t + q * 256;
    float s = score[(g << 10) + n] * inv;
    sc[n] = s;
    srt[n] = (gate[(g << 10) + n] != 0.f) ? s : -3.402823466e38f;
  }
  __syncthreads();
  for (int k2 = 2; k2 <= NPG; k2 <<= 1) {
    for (int j = k2 >> 1; j > 0; j >>= 1) {
#pragma unroll
      for (int q = 0; q < 4; ++q) {
        int i = t + q * 256;
        int l = i ^ j;
        if (l > i) {
          float a = srt[i], b = srt[l];
          if ((a > b) == ((i & k2) == 0)) { srt[i] = b; srt[l] = a; }
        }
      }
      __syncthreads();
    }
  }
  float thr = srt[NPG - kk];
#pragma unroll
  for (int q = 0; q < 4; ++q) {
    int n = t + q * 256;
    float s = sc[n];
    bool sel = (gate[(g << 10) + n] != 0.f) && (s >= thr);
    gate[(g << 10) + n] = sel ? tanhf(s) : 0.f;
  }
}

// ---------------------------------------------------------------------------
// Pool stage 1: block (g, c) sums gate-weighted rows [c*128, c*128+128) of
// graph g -> part[g*1024 + c*128 + f]. 1024 blocks, coalesced.
__global__ __launch_bounds__(256) void pool1_kernel(const float* __restrict__ X,
                                                    const float* __restrict__ gate,
                                                    float* __restrict__ part) {
  __shared__ float gs[128];
  __shared__ float ps[2][HD];
  int b = blockIdx.x;
  int g = b >> 3, c = b & 7;
  int t = threadIdx.x;
  if (t < 128) gs[t] = gate[(g << 10) + c * 128 + t];
  __syncthreads();
  int f = t & 127, sub = t >> 7;
  size_t base = (size_t)((g << 10) + c * 128) * HD;
  float s = 0.f;
  for (int r = sub; r < 128; r += 2)
    s += X[base + (size_t)r * HD + f] * gs[r];
  ps[sub][f] = s;
  __syncthreads();
  if (t < 128) part[(g << 10) + c * 128 + t] = ps[0][t] + ps[1][t];
}

// ---------------------------------------------------------------------------
// Pool stage 2 + MLP + log_softmax (divisor exactly K3).
__global__ __launch_bounds__(128) void final2_kernel(const float* __restrict__ part,
                                                     const float* __restrict__ Wf1,
                                                     const float* __restrict__ bf1,
                                                     const float* __restrict__ Wf2,
                                                     const float* __restrict__ bf2,
                                                     float* __restrict__ out) {
  __shared__ float pl[HD];
  __shared__ float h1[64];
  __shared__ float lg[10];
  __shared__ float red[2];
  int g = blockIdx.x, t = threadIdx.x;
  float tot = 0.f;
#pragma unroll
  for (int c = 0; c < 8; ++c) tot += part[(g << 10) + c * 128 + t];
  pl[t] = tot / (float)KS3;
  __syncthreads();
  if (t < 64) {
    float h = bf1[t];
    for (int ff = 0; ff < HD; ++ff) h += pl[ff] * Wf1[t * HD + ff];
    h1[t] = fmaxf(h, 0.f);
  }
  __syncthreads();
  if (t < 10) {
    float z = bf2[t];
    for (int j = 0; j < 64; ++j) z += h1[j] * Wf2[t * 64 + j];
    lg[t] = z;
  }
  __syncthreads();
  if (t == 0) {
    float m = lg[0];
    for (int cc = 1; cc < 10; ++cc) m = fmaxf(m, lg[cc]);
    float ssum = 0.f;
    for (int cc = 0; cc < 10; ++cc) ssum += expf(lg[cc] - m);
    red[0] = m; red[1] = logf(ssum);
  }
  __syncthreads();
  if (t < 10) out[g * 10 + t] = lg[t] - red[0] - red[1];
}

// ---------------------------------------------------------------------------
extern "C" void kernel_launch(void* const* d_in, const int* in_sizes, int n_in,
                              void* d_out, int out_size, void* d_ws, size_t ws_size,
                              hipStream_t stream) {
  const float* x  = (const float*)d_in[0];
  int* ei         = (int*)d_in[1];          // src half becomes CSR after csr_build
  const float* Wl[3]  = {(const float*)d_in[2], (const float*)d_in[6],  (const float*)d_in[10]};
  const float* blv[3] = {(const float*)d_in[3], (const float*)d_in[7],  (const float*)d_in[11]};
  const float* Wr[3]  = {(const float*)d_in[4], (const float*)d_in[8],  (const float*)d_in[12]};
  const float* wp[3]  = {(const float*)d_in[5], (const float*)d_in[9],  (const float*)d_in[13]};
  const float* Wf1 = (const float*)d_in[14];
  const float* bf1 = (const float*)d_in[15];
  const float* Wf2 = (const float*)d_in[16];
  const float* bf2 = (const float*)d_in[17];
  float* out = (float*)d_out;

  // workspace: bufA (64MB) | bufB (64MB) | gate (512KB) | score (512KB) | Wcvt (384KB)
  float* bufA  = (float*)d_ws;
  float* bufB  = bufA + (size_t)NN * HD;
  float* gate  = bufB + (size_t)NN * HD;
  float* score = gate + NN;             // reused as pool partials at the end
  _Float16* Wcvt = (_Float16*)(score + NN);

  init_gate<<<NN / 256, 256, 0, stream>>>(gate);
  wconv<<<384, 256, 0, stream>>>(Wl[0], Wr[0], Wl[1], Wr[1], Wl[2], Wr[2], Wcvt);
  csr_build<<<NGPH, 1024, 0, stream>>>(ei);

  // L1: x -> mean(bufA) -> gemm in-place bufA (+score) -> topk (gate only)
  agg3_kernel<<<NN / 4, 256, 0, stream>>>(x, ei, gate, bufA);
  gemm_mfma<<<NN / 128, 256, 0, stream>>>(bufA, x, Wcvt, blv[0], wp[0], gate, bufA, score);
  topk_kernel<<<NGPH, 256, 0, stream>>>(score, gate, wp[0], KS1);
  // L2
  agg3_kernel<<<NN / 4, 256, 0, stream>>>(bufA, ei, gate, bufB);
  gemm_mfma<<<NN / 128, 256, 0, stream>>>(bufB, bufA, Wcvt + 65536, blv[1], wp[1], gate, bufB, score);
  topk_kernel<<<NGPH, 256, 0, stream>>>(score, gate, wp[1], KS2);
  // L3
  agg3_kernel<<<NN / 4, 256, 0, stream>>>(bufB, ei, gate, bufA);
  gemm_mfma<<<NN / 128, 256, 0, stream>>>(bufA, bufB, Wcvt + 131072, blv[2], wp[2], gate, bufA, score);
  topk_kernel<<<NGPH, 256, 0, stream>>>(score, gate, wp[2], KS3);

  pool1_kernel<<<NGPH * 8, 256, 0, stream>>>(bufA, gate, score);
  final2_kernel<<<NGPH, 128, 0, stream>>>(score, Wf1, bf1, Wf2, bf2, out);
}